// Round 14
// baseline (349.381 us; speedup 1.0000x reference)
//
#include <hip/hip_runtime.h>
#include <cstdint>

#define N_NODES 100000
#define N_EDGES 1600000
#define NEG_SLOPE 0.2f

#define NBUCK 391          // ceil(100000/256), bucket = dst >> 8
#define NCHUNK 128
#define CHUNK_SZ ((N_EDGES + NCHUNK - 1) / NCHUNK)   // 12500

typedef short s16x8 __attribute__((ext_vector_type(8)));
typedef float f32x4 __attribute__((ext_vector_type(4)));
typedef float f32x2 __attribute__((ext_vector_type(2)));

#if defined(__has_builtin)
#if __has_builtin(__builtin_amdgcn_cvt_pk_f32_fp8) && __has_builtin(__builtin_amdgcn_cvt_pk_fp8_f32)
#define HAS_HW_FP8 1
#endif
#endif

__device__ inline float bf2f(ushort u) {
    union { uint i; float f; } x; x.i = ((uint)u) << 16; return x.f;
}
__device__ inline ushort f2bf(float f) {
    union { float f; uint i; } x; x.f = f;
    uint r = x.i + 0x7FFF + ((x.i >> 16) & 1);   // RNE
    return (ushort)(r >> 16);
}
__device__ inline float lrelu(float e) { return (e > 0.f) ? e : NEG_SLOPE * e; }

// ---- manual OCP e4m3fn encode/decode (fallback path) ----
__device__ inline uint f2e4m3(float f) {
    uint bits = __float_as_uint(f);
    uint s = (bits >> 24) & 0x80;
    float af = __uint_as_float(bits & 0x7FFFFFFF);
    af = fminf(af, 448.f);
    uint out;
    if (af < 0.015625f) {
        out = (uint)rintf(af * 512.f);
    } else {
        uint ab = __float_as_uint(af);
        uint r = ab + 0x0007FFFFu + ((ab >> 20) & 1u);
        int e2 = (int)((r >> 23) & 0xFF) - 127;
        uint m3 = (r >> 20) & 7u;
        if (e2 > 8) { e2 = 8; m3 = 6; }
        out = ((uint)(e2 + 7) << 3) | m3;
    }
    return s | out;
}
__device__ inline float e4m32f(uint u) {
    uint exp = (u >> 3) & 0xF;
    uint m = u & 7u;
    float mant = (float)((exp ? 8u : 0u) | m);
    uint e = (exp ? exp : 1u) + 117u;
    float v = mant * __uint_as_float(e << 23);
    return (u & 0x80) ? -v : v;
}

__device__ inline uchar enc8(float v) {
#ifdef HAS_HW_FP8
    return (uchar)(__builtin_amdgcn_cvt_pk_fp8_f32(v, v, 0, false) & 0xFF);
#else
    return (uchar)f2e4m3(v);
#endif
}

// accumulate 4 fp8 (one uint) weighted by a2 into two f32x2 accumulators
__device__ inline void acc4(f32x2 a2, uint w, f32x2& lo, f32x2& hi) {
#ifdef HAS_HW_FP8
    f32x2 p0 = __builtin_amdgcn_cvt_pk_f32_fp8((int)w, false);
    f32x2 p1 = __builtin_amdgcn_cvt_pk_f32_fp8((int)w, true);
    lo += a2 * p0;
    hi += a2 * p1;
#else
    lo[0] += a2[0] * e4m32f(w & 255);
    lo[1] += a2[1] * e4m32f((w >> 8) & 255);
    hi[0] += a2[0] * e4m32f((w >> 16) & 255);
    hi[1] += a2[1] * e4m32f(w >> 24);
#endif
}

// ---------------- CSR build: 2-level bucket counting sort (packed pairs) ----------------

__global__ __launch_bounds__(256) void bucket_hist(const int* __restrict__ dst,
                                                   int* __restrict__ chunkCnt) {
    __shared__ int cnt[NBUCK];
    int t = threadIdx.x, blk = blockIdx.x;
    for (int b = t; b < NBUCK; b += 256) cnt[b] = 0;
    __syncthreads();
    int beg = blk * CHUNK_SZ, end = min(beg + CHUNK_SZ, N_EDGES);
    for (int i = beg + t; i < end; i += 256) atomicAdd(&cnt[dst[i] >> 8], 1);
    __syncthreads();
    for (int b = t; b < NBUCK; b += 256) chunkCnt[blk * NBUCK + b] = cnt[b];
}

__global__ __launch_bounds__(512) void bucket_scan(const int* __restrict__ chunkCnt,
                                                   int* __restrict__ chunkBase,
                                                   int* __restrict__ bucketBase) {
    __shared__ int tot[512];
    int b = threadIdx.x;
    int run = 0;
    if (b < NBUCK) {
        for (int c = 0; c < NCHUNK; ++c) {
            chunkBase[c * NBUCK + b] = run;
            run += chunkCnt[c * NBUCK + b];
        }
    }
    tot[b] = (b < NBUCK) ? run : 0;
    __syncthreads();
    for (int off = 1; off < 512; off <<= 1) {
        int x = (b >= off) ? tot[b - off] : 0;
        __syncthreads();
        tot[b] += x;
        __syncthreads();
    }
    if (b == 0) bucketBase[0] = 0;
    if (b < NBUCK) bucketBase[b + 1] = tot[b];
}

__global__ __launch_bounds__(256) void bucket_scatter(const int* __restrict__ src,
                                                      const int* __restrict__ dst,
                                                      const int* __restrict__ chunkBase,
                                                      const int* __restrict__ bucketBase,
                                                      int* __restrict__ pairs) {
    __shared__ int cur[NBUCK];
    int t = threadIdx.x, blk = blockIdx.x;
    for (int b = t; b < NBUCK; b += 256)
        cur[b] = bucketBase[b] + chunkBase[blk * NBUCK + b];
    __syncthreads();
    int beg = blk * CHUNK_SZ, end = min(beg + CHUNK_SZ, N_EDGES);
    for (int i = beg + t; i < end; i += 256) {
        int d = dst[i];
        int pos = atomicAdd(&cur[d >> 8], 1);
        pairs[pos] = (src[i] << 8) | (d & 255);
    }
}

__global__ __launch_bounds__(256) void bucket_build(const int* __restrict__ pairs,
                                                    const int* __restrict__ bucketBase,
                                                    int* __restrict__ rowptr,
                                                    int* __restrict__ csr) {
    __shared__ int cnt[256], pre[256];
    int b = blockIdx.x, t = threadIdx.x;
    cnt[t] = 0;
    __syncthreads();
    int beg = bucketBase[b], end = bucketBase[b + 1];
    for (int i = beg + t; i < end; i += 256) atomicAdd(&cnt[pairs[i] & 255], 1);
    __syncthreads();
    int v = cnt[t];
    pre[t] = v;
    __syncthreads();
    for (int off = 1; off < 256; off <<= 1) {
        int x = (t >= off) ? pre[t - off] : 0;
        __syncthreads();
        pre[t] += x;
        __syncthreads();
    }
    int excl = pre[t] - v;
    int node = b * 256 + t;
    if (node <= N_NODES) rowptr[node] = beg + excl;
    cnt[t] = excl;
    __syncthreads();
    for (int i = beg + t; i < end; i += 256) {
        int p = pairs[i];
        int pos = beg + atomicAdd(&cnt[p & 255], 1);
        csr[pos] = p >> 8;
    }
}

// ---------------- merged weight transpose/convert (W1+W2+W3) ----------------
__global__ void transpose_w_all(const float* __restrict__ W1, const float* __restrict__ W2,
                                const float* __restrict__ W3, ushort* __restrict__ BT1,
                                ushort* __restrict__ BT2, ushort* __restrict__ BT3) {
    int i = blockIdx.x * blockDim.x + threadIdx.x;
    if (i < 32768) {                       // W1 [256][128] -> BT1 [128][256]
        int n = i >> 8, k = i & 255;
        BT1[i] = f2bf(W1[(size_t)k * 128 + n]);
    } else if (i < 49152) {                // W2 [128][128] -> BT2 [128][128]
        int j = i - 32768;
        int n = j >> 7, k = j & 127;
        BT2[j] = f2bf(W2[(size_t)k * 128 + n]);
    } else if (i < 55296) {                // W3 [128][40] -> BT3 [48][128] (pad)
        int j = i - 49152;
        int n = j >> 7, k = j & 127;
        BT3[j] = f2bf((n < 40) ? W3[(size_t)k * 40 + n] : 0.f);
    }
}

// ---------------- GEMM1: fp32 X (K=256) -> fp8 table + As/Ad (4 heads) ----------------

__global__ __launch_bounds__(256) void mfma_gemm1(const float* __restrict__ X,
                                                  const ushort* __restrict__ BT,
                                                  const float* __restrict__ asv,
                                                  const float* __restrict__ adv,
                                                  uchar* __restrict__ X8,
                                                  float* __restrict__ As,
                                                  float* __restrict__ Ad) {
    __shared__ ushort Ats[64][40];
    __shared__ ushort Bs[128][40];
    __shared__ float sA[64][4], sD[64][4];
    int m0 = blockIdx.x * 64;
    int t = threadIdx.x;
    int wave = t >> 6, lane = t & 63;
    int wm = wave >> 1, wn = wave & 1;
    f32x4 acc[2][4] = {};
    for (int kt = 0; kt < 256; kt += 32) {
        {
            int r = t >> 2, kg = (t & 3) << 3;
            int rr = (m0 + r < N_NODES) ? m0 + r : N_NODES - 1;
            float4 xa = *(const float4*)&X[(size_t)rr * 256 + kt + kg];
            float4 xb = *(const float4*)&X[(size_t)rr * 256 + kt + kg + 4];
            ushort o[8] = { f2bf(xa.x), f2bf(xa.y), f2bf(xa.z), f2bf(xa.w),
                            f2bf(xb.x), f2bf(xb.y), f2bf(xb.z), f2bf(xb.w) };
            *(s16x8*)&Ats[r][kg] = *(s16x8*)o;
        }
        #pragma unroll
        for (int i = 0; i < 2; ++i) {
            int idx = t + (i << 8);
            int r = idx >> 2, kg = (idx & 3) << 3;
            *(s16x8*)&Bs[r][kg] = *(const s16x8*)&BT[(size_t)r * 256 + kt + kg];
        }
        __syncthreads();
        int row = lane & 15, koff = (lane >> 4) << 3;
        s16x8 a[2], b[4];
        #pragma unroll
        for (int mf = 0; mf < 2; ++mf)
            a[mf] = *(s16x8*)&Ats[wm * 32 + mf * 16 + row][koff];
        #pragma unroll
        for (int nf = 0; nf < 4; ++nf)
            b[nf] = *(s16x8*)&Bs[wn * 64 + nf * 16 + row][koff];
        #pragma unroll
        for (int mf = 0; mf < 2; ++mf)
            #pragma unroll
            for (int nf = 0; nf < 4; ++nf)
                acc[mf][nf] = __builtin_amdgcn_mfma_f32_16x16x32_bf16(a[mf], b[nf], acc[mf][nf], 0, 0, 0);
        __syncthreads();
    }
    int colb = lane & 15, rowb = (lane >> 4) << 2;
    float a0 = asv[wn * 64 + colb],      d0 = adv[wn * 64 + colb];
    float a1 = asv[wn * 64 + 16 + colb], d1 = adv[wn * 64 + 16 + colb];
    float a2 = asv[wn * 64 + 32 + colb], d2 = adv[wn * 64 + 32 + colb];
    float a3 = asv[wn * 64 + 48 + colb], d3 = adv[wn * 64 + 48 + colb];
    #pragma unroll
    for (int mf = 0; mf < 2; ++mf)
        #pragma unroll
        for (int reg = 0; reg < 4; ++reg) {
            float v0 = acc[mf][0][reg], v1 = acc[mf][1][reg];
            float v2 = acc[mf][2][reg], v3 = acc[mf][3][reg];
            float sLo = v0 * a0 + v1 * a1, sHi = v2 * a2 + v3 * a3;
            float dLo = v0 * d0 + v1 * d1, dHi = v2 * d2 + v3 * d3;
            #pragma unroll
            for (int off = 1; off < 16; off <<= 1) {
                sLo += __shfl_xor(sLo, off, 64); sHi += __shfl_xor(sHi, off, 64);
                dLo += __shfl_xor(dLo, off, 64); dHi += __shfl_xor(dHi, off, 64);
            }
            if (colb == 0) {
                int r = wm * 32 + mf * 16 + rowb + reg;
                sA[r][wn * 2] = sLo; sA[r][wn * 2 + 1] = sHi;
                sD[r][wn * 2] = dLo; sD[r][wn * 2 + 1] = dHi;
            }
        }
    #pragma unroll
    for (int mf = 0; mf < 2; ++mf)
        #pragma unroll
        for (int nf = 0; nf < 4; ++nf)
            #pragma unroll
            for (int reg = 0; reg < 4; ++reg) {
                int row = m0 + wm * 32 + mf * 16 + rowb + reg;
                int col = wn * 64 + nf * 16 + colb;
                if (row < N_NODES) X8[(size_t)row * 128 + col] = enc8(acc[mf][nf][reg]);
            }
    __syncthreads();
    {
        int r = t >> 2, h = t & 3;
        int node = m0 + r;
        if (node < N_NODES) {
            As[(size_t)node * 4 + h] = sA[r][h];
            Ad[(size_t)node * 4 + h] = sD[r][h];
        }
    }
}

// ---------------- GEMM2: bf16 in (K=128) -> fp8 table + As/Ad (1 head) ----------------

__global__ __launch_bounds__(256) void mfma_gemm2(const ushort* __restrict__ X,
                                                  const ushort* __restrict__ BT,
                                                  const float* __restrict__ asv,
                                                  const float* __restrict__ adv,
                                                  uchar* __restrict__ X8,
                                                  float* __restrict__ As,
                                                  float* __restrict__ Ad) {
    __shared__ ushort Ats[64][40];
    __shared__ ushort Bs[128][40];
    __shared__ float sA1[64], sD1[64];
    int m0 = blockIdx.x * 64;
    int t = threadIdx.x;
    int wave = t >> 6, lane = t & 63;
    int wm = wave >> 1, wn = wave & 1;
    f32x4 acc[2][4] = {};
    for (int kt = 0; kt < 128; kt += 32) {
        {
            int r = t >> 2, kg = (t & 3) << 3;
            *(s16x8*)&Ats[r][kg] = *(const s16x8*)&X[(size_t)(m0 + r) * 128 + kt + kg];
        }
        #pragma unroll
        for (int i = 0; i < 2; ++i) {
            int idx = t + (i << 8);
            int r = idx >> 2, kg = (idx & 3) << 3;
            *(s16x8*)&Bs[r][kg] = *(const s16x8*)&BT[(size_t)r * 128 + kt + kg];
        }
        __syncthreads();
        int row = lane & 15, koff = (lane >> 4) << 3;
        s16x8 a[2], b[4];
        #pragma unroll
        for (int mf = 0; mf < 2; ++mf)
            a[mf] = *(s16x8*)&Ats[wm * 32 + mf * 16 + row][koff];
        #pragma unroll
        for (int nf = 0; nf < 4; ++nf)
            b[nf] = *(s16x8*)&Bs[wn * 64 + nf * 16 + row][koff];
        #pragma unroll
        for (int mf = 0; mf < 2; ++mf)
            #pragma unroll
            for (int nf = 0; nf < 4; ++nf)
                acc[mf][nf] = __builtin_amdgcn_mfma_f32_16x16x32_bf16(a[mf], b[nf], acc[mf][nf], 0, 0, 0);
        __syncthreads();
    }
    if (t < 64) { sA1[t] = 0.f; sD1[t] = 0.f; }
    __syncthreads();
    int colb = lane & 15, rowb = (lane >> 4) << 2;
    float a0 = asv[wn * 64 + colb],      d0 = adv[wn * 64 + colb];
    float a1 = asv[wn * 64 + 16 + colb], d1 = adv[wn * 64 + 16 + colb];
    float a2 = asv[wn * 64 + 32 + colb], d2 = adv[wn * 64 + 32 + colb];
    float a3 = asv[wn * 64 + 48 + colb], d3 = adv[wn * 64 + 48 + colb];
    #pragma unroll
    for (int mf = 0; mf < 2; ++mf)
        #pragma unroll
        for (int reg = 0; reg < 4; ++reg) {
            float v0 = acc[mf][0][reg], v1 = acc[mf][1][reg];
            float v2 = acc[mf][2][reg], v3 = acc[mf][3][reg];
            float s = v0 * a0 + v1 * a1 + v2 * a2 + v3 * a3;
            float d = v0 * d0 + v1 * d1 + v2 * d2 + v3 * d3;
            #pragma unroll
            for (int off = 1; off < 16; off <<= 1) {
                s += __shfl_xor(s, off, 64);
                d += __shfl_xor(d, off, 64);
            }
            if (colb == 0) {
                int r = wm * 32 + mf * 16 + rowb + reg;
                atomicAdd(&sA1[r], s);
                atomicAdd(&sD1[r], d);
            }
        }
    #pragma unroll
    for (int mf = 0; mf < 2; ++mf)
        #pragma unroll
        for (int nf = 0; nf < 4; ++nf)
            #pragma unroll
            for (int reg = 0; reg < 4; ++reg) {
                int row = m0 + wm * 32 + mf * 16 + rowb + reg;
                int col = wn * 64 + nf * 16 + colb;
                if (row < N_NODES) X8[(size_t)row * 128 + col] = enc8(acc[mf][nf][reg]);
            }
    __syncthreads();
    if (t < 64) {
        int node = m0 + t;
        if (node < N_NODES) { As[node] = sA1[t]; Ad[node] = sD1[t]; }
    }
}

// ---------------- GEMM3: bf16 in (K=128), 40 cols -> fp8 table (stride 64) + As/Ad ----------------

__global__ __launch_bounds__(256) void mfma_gemm3(const ushort* __restrict__ X,
                                                  const ushort* __restrict__ BT,
                                                  const float* __restrict__ asv,
                                                  const float* __restrict__ adv,
                                                  uchar* __restrict__ X8,
                                                  float* __restrict__ As,
                                                  float* __restrict__ Ad) {
    __shared__ ushort Ats[64][40];
    __shared__ ushort Bs[48][40];
    int m0 = blockIdx.x * 64;
    int t = threadIdx.x, wave = t >> 6, lane = t & 63;
    f32x4 acc[3] = {};
    for (int kt = 0; kt < 128; kt += 32) {
        {
            int r = t >> 2, kg = (t & 3) << 3;
            *(s16x8*)&Ats[r][kg] = *(const s16x8*)&X[(size_t)(m0 + r) * 128 + kt + kg];
        }
        if (t < 192) {
            int r = t >> 2, kg = (t & 3) << 3;
            *(s16x8*)&Bs[r][kg] = *(const s16x8*)&BT[(size_t)r * 128 + kt + kg];
        }
        __syncthreads();
        int row = lane & 15, koff = (lane >> 4) << 3;
        s16x8 a = *(s16x8*)&Ats[wave * 16 + row][koff];
        #pragma unroll
        for (int nf = 0; nf < 3; ++nf) {
            s16x8 b = *(s16x8*)&Bs[nf * 16 + row][koff];
            acc[nf] = __builtin_amdgcn_mfma_f32_16x16x32_bf16(a, b, acc[nf], 0, 0, 0);
        }
        __syncthreads();
    }
    int colb = lane & 15, rowb = (lane >> 4) << 2;
    float a0 = asv[colb],      d0 = adv[colb];
    float a1 = asv[16 + colb], d1 = adv[16 + colb];
    float a2 = (32 + colb < 40) ? asv[32 + colb] : 0.f;
    float d2 = (32 + colb < 40) ? adv[32 + colb] : 0.f;
    #pragma unroll
    for (int reg = 0; reg < 4; ++reg) {
        float s = acc[0][reg] * a0 + acc[1][reg] * a1 + acc[2][reg] * a2;
        float d = acc[0][reg] * d0 + acc[1][reg] * d1 + acc[2][reg] * d2;
        #pragma unroll
        for (int off = 1; off < 16; off <<= 1) {
            s += __shfl_xor(s, off, 64);
            d += __shfl_xor(d, off, 64);
        }
        if (colb == 0) {
            int node = m0 + wave * 16 + rowb + reg;
            if (node < N_NODES) { As[node] = s; Ad[node] = d; }
        }
    }
    #pragma unroll
    for (int nf = 0; nf < 3; ++nf)
        #pragma unroll
        for (int reg = 0; reg < 4; ++reg) {
            int row = m0 + wave * 16 + rowb + reg;
            int col = nf * 16 + colb;
            if (row < N_NODES) X8[(size_t)row * 64 + col] = enc8(acc[nf][reg]);
        }
}

// ---------------- single-pass aggregate from fp8 table (WD=128) ----------------
// 8 lanes cover a 128B row (16B uint4 each); 8 rows per round.

template <int NH>
__global__ void agg_fused_fp8(const uchar* __restrict__ X8, const float* __restrict__ As,
                              const float* __restrict__ Ad, const float* __restrict__ bias,
                              const int* __restrict__ rowptr, const int* __restrict__ csr,
                              ushort* __restrict__ Y) {
    int node = (int)((blockIdx.x * blockDim.x + threadIdx.x) >> 6);
    int lane = threadIdx.x & 63;
    if (node >= N_NODES) return;
    int sub = lane >> 3;            // 0..7: row within round
    int cg = (lane & 7) << 4;       // col group: 16 fp8 = 16B
    int hB = (NH == 4) ? (cg >> 5) : 0;
    float adiB = Ad[(size_t)node * NH + hB];
    int beg = rowptr[node], deg = rowptr[node + 1] - beg;
    int items = deg + 1;
    f32x2 acc2[8] = {};
    float den = 0.f;
    for (int base = 0; base < items; base += 8) {
        int i = base + sub;
        int src = (i < deg) ? csr[beg + i] : node;
        float e = As[(size_t)src * NH + hB] + adiB;
        float a = __expf(lrelu(e));
        if (i > deg) a = 0.f;
        den += a;
        f32x2 a2 = { a, a };
        uint4 rv = *(const uint4*)(X8 + (((uint)src << 7) + cg));
        acc4(a2, rv.x, acc2[0], acc2[1]);
        acc4(a2, rv.y, acc2[2], acc2[3]);
        acc4(a2, rv.z, acc2[4], acc2[5]);
        acc4(a2, rv.w, acc2[6], acc2[7]);
    }
    den += __shfl_xor(den, 8, 64);
    den += __shfl_xor(den, 16, 64);
    den += __shfl_xor(den, 32, 64);
    float* af = (float*)acc2;
    #pragma unroll
    for (int k = 0; k < 16; ++k) {
        af[k] += __shfl_xor(af[k], 8, 64);
        af[k] += __shfl_xor(af[k], 16, 64);
        af[k] += __shfl_xor(af[k], 32, 64);
    }
    if (sub == 0) {                 // lanes 0..7 write cols cg..cg+15 (bf16, 32B)
        float dinv = 1.0f / den;
        uint o[8];
        #pragma unroll
        for (int k = 0; k < 8; ++k) {
            float v0 = fmaxf(acc2[k][0] * dinv + bias[cg + 2 * k],     0.f);
            float v1 = fmaxf(acc2[k][1] * dinv + bias[cg + 2 * k + 1], 0.f);
            o[k] = (uint)f2bf(v0) | ((uint)f2bf(v1) << 16);
        }
        *reinterpret_cast<uint4*>(&Y[(size_t)node * 128 + cg]) = *reinterpret_cast<uint4*>(&o[0]);
        *reinterpret_cast<uint4*>(&Y[(size_t)node * 128 + cg + 8]) = *reinterpret_cast<uint4*>(&o[4]);
    }
}

// ---------------- single-pass aggregate + log-softmax (layer 3, fp8 stride-64) ----------------
// 4 lanes cover a 64B row (16B each); 16 rows per round.

__global__ void agg_l3_fp8(const uchar* __restrict__ X8, const float* __restrict__ As,
                           const float* __restrict__ Ad, const float* __restrict__ bias,
                           const int* __restrict__ rowptr, const int* __restrict__ csr,
                           float* __restrict__ Y) {
    int node = (int)((blockIdx.x * blockDim.x + threadIdx.x) >> 6);
    int lane = threadIdx.x & 63;
    if (node >= N_NODES) return;
    int sub = lane >> 2;            // 0..15: row within round
    int cg = (lane & 3) << 4;       // col group: 16 fp8 = 16B
    float adi = Ad[node];
    int beg = rowptr[node], deg = rowptr[node + 1] - beg;
    int items = deg + 1;
    f32x2 acc2[8] = {};
    float den = 0.f;
    for (int base = 0; base < items; base += 16) {
        int i = base + sub;
        int src = (i < deg) ? csr[beg + i] : node;
        float a = __expf(lrelu(As[src] + adi));
        if (i > deg) a = 0.f;
        den += a;
        f32x2 a2 = { a, a };
        uint4 rv = *(const uint4*)(X8 + (((uint)src << 6) + cg));
        acc4(a2, rv.x, acc2[0], acc2[1]);
        acc4(a2, rv.y, acc2[2], acc2[3]);
        acc4(a2, rv.z, acc2[4], acc2[5]);
        acc4(a2, rv.w, acc2[6], acc2[7]);
    }
    den += __shfl_xor(den, 4, 64);
    den += __shfl_xor(den, 8, 64);
    den += __shfl_xor(den, 16, 64);
    den += __shfl_xor(den, 32, 64);
    float* af = (float*)acc2;
    #pragma unroll
    for (int k = 0; k < 16; ++k) {
        af[k] += __shfl_xor(af[k], 4, 64);
        af[k] += __shfl_xor(af[k], 8, 64);
        af[k] += __shfl_xor(af[k], 16, 64);
        af[k] += __shfl_xor(af[k], 32, 64);
    }
    // lanes 0..2 hold valid col-groups (cols 0..39 within cg..cg+15)
    bool anyv = (lane < 3);
    float v[16];
    float pm = -1e30f;
    if (anyv) {
        float dinv = 1.0f / den;
        #pragma unroll
        for (int k = 0; k < 16; ++k) {
            int col = cg + k;
            v[k] = (col < 40) ? (af[k] * dinv + bias[col]) : -1e30f;
            pm = fmaxf(pm, v[k]);
        }
    }
    pm = fmaxf(pm, __shfl_xor(pm, 1, 64));
    pm = fmaxf(pm, __shfl_xor(pm, 2, 64));
    float ps = 0.f;
    if (anyv) {
        #pragma unroll
        for (int k = 0; k < 16; ++k) {
            int col = cg + k;
            if (col < 40) ps += __expf(v[k] - pm);
        }
    }
    ps += __shfl_xor(ps, 1, 64);
    ps += __shfl_xor(ps, 2, 64);
    if (anyv) {
        float lden = __logf(ps);
        #pragma unroll
        for (int q = 0; q < 4; ++q) {
            int col0 = cg + q * 4;
            if (col0 < 40) {
                float4 o = make_float4(v[q * 4] - pm - lden, v[q * 4 + 1] - pm - lden,
                                       v[q * 4 + 2] - pm - lden, v[q * 4 + 3] - pm - lden);
                *reinterpret_cast<float4*>(&Y[(size_t)node * 40 + col0]) = o;
            }
        }
    }
}

// ---------------- launch ----------------

static inline size_t align256(size_t x) { return (x + 255) & ~(size_t)255; }

extern "C" void kernel_launch(void* const* d_in, const int* in_sizes, int n_in,
                              void* d_out, int out_size, void* d_ws, size_t ws_size,
                              hipStream_t stream) {
    const int*   edge = (const int*)d_in[0];
    const float* feat = (const float*)d_in[1];
    const float* W1   = (const float*)d_in[2];
    const float* as1  = (const float*)d_in[3];
    const float* ad1  = (const float*)d_in[4];
    const float* b1   = (const float*)d_in[5];
    const float* W2   = (const float*)d_in[6];
    const float* as2  = (const float*)d_in[7];
    const float* ad2  = (const float*)d_in[8];
    const float* b2   = (const float*)d_in[9];
    const float* W3   = (const float*)d_in[10];
    const float* as3  = (const float*)d_in[11];
    const float* ad3  = (const float*)d_in[12];
    const float* b3   = (const float*)d_in[13];
    float* out = (float*)d_out;

    const int* srcArr = edge;
    const int* dstArr = edge + N_EDGES;

    const size_t NB128 = (size_t)N_NODES * 128 * 2;   // 25.6 MB

    char* w = (char*)d_ws;
    char* regionA = w; w += align256(2 * NB128);      // pairs -> x8_2 | h2
    char* regionB = w; w += align256(NB128);          // x8_1 ; x8_3 at +NB128/2
    char* regionC = w; w += align256(NB128);          // h1
    float* As   = (float*)w; w += align256((size_t)N_NODES * 4 * 4);
    float* Ad   = (float*)w; w += align256((size_t)N_NODES * 4 * 4);
    int* rowptr = (int*)w;   w += align256((size_t)(N_NODES + 1) * 4);
    int* csr    = (int*)w;   w += align256((size_t)N_EDGES * 4);
    int* chunkCnt  = (int*)w; w += align256((size_t)NCHUNK * NBUCK * 4);
    int* chunkBase = (int*)w; w += align256((size_t)NCHUNK * NBUCK * 4);
    int* bucketBase = (int*)w; w += align256((size_t)(NBUCK + 1) * 4);
    ushort* WT1 = (ushort*)w; w += align256((size_t)128 * 256 * 2);
    ushort* WT2 = (ushort*)w; w += align256((size_t)128 * 128 * 2);
    ushort* WT3 = (ushort*)w; w += align256((size_t)48 * 128 * 2);

    int* pairs = (int*)regionA;                       // packed, dead before x8_2

    uchar*  x8_1 = (uchar*)regionB;                   // [100k][128] fp8
    uchar*  x8_3 = (uchar*)(regionB + NB128 / 2);     // [100k][64]  fp8
    ushort* h1   = (ushort*)regionC;                  // [100k][128] bf16
    uchar*  x8_2 = (uchar*)regionA;                   // [100k][128] fp8
    ushort* h2   = (ushort*)(regionA + NB128);        // [100k][128] bf16

    // ---- CSR build ----
    bucket_hist<<<NCHUNK, 256, 0, stream>>>(dstArr, chunkCnt);
    bucket_scan<<<1, 512, 0, stream>>>(chunkCnt, chunkBase, bucketBase);
    bucket_scatter<<<NCHUNK, 256, 0, stream>>>(srcArr, dstArr, chunkBase, bucketBase, pairs);
    bucket_build<<<NBUCK, 256, 0, stream>>>(pairs, bucketBase, rowptr, csr);

    // weights (merged)
    transpose_w_all<<<(55296 + 255) / 256, 256, 0, stream>>>(W1, W2, W3, WT1, WT2, WT3);

    int aggGrid = (N_NODES + 3) / 4;
    int gemmGrid = (N_NODES + 63) / 64;

    // ---- layer 1 ----
    mfma_gemm1<<<gemmGrid, 256, 0, stream>>>(feat, WT1, as1, ad1, x8_1, As, Ad);
    agg_fused_fp8<4><<<aggGrid, 256, 0, stream>>>(x8_1, As, Ad, b1, rowptr, csr, h1);

    // ---- layer 2 ----
    mfma_gemm2<<<gemmGrid, 256, 0, stream>>>(h1, WT2, as2, ad2, x8_2, As, Ad);
    agg_fused_fp8<1><<<aggGrid, 256, 0, stream>>>(x8_2, As, Ad, b2, rowptr, csr, h2);

    // ---- layer 3 ----
    mfma_gemm3<<<gemmGrid, 256, 0, stream>>>(h2, WT3, as3, ad3, x8_3, As, Ad);
    agg_l3_fp8<<<aggGrid, 256, 0, stream>>>(x8_3, As, Ad, b3, rowptr, csr, out);
}

// Round 16
// 310.009 us; speedup vs baseline: 1.1270x; 1.1270x over previous
//
#include <hip/hip_runtime.h>
#include <cstdint>

#define N_NODES 100000
#define N_EDGES 1600000
#define NEG_SLOPE 0.2f

#define NBUCK 391          // ceil(100000/256), bucket = dst >> 8
#define NCHUNK 128
#define CHUNK_SZ ((N_EDGES + NCHUNK - 1) / NCHUNK)   // 12500

typedef short s16x8 __attribute__((ext_vector_type(8)));
typedef float f32x4 __attribute__((ext_vector_type(4)));
typedef float f32x2 __attribute__((ext_vector_type(2)));

#if defined(__has_builtin)
#if __has_builtin(__builtin_amdgcn_cvt_pk_f32_fp8) && __has_builtin(__builtin_amdgcn_cvt_pk_fp8_f32)
#define HAS_HW_FP8 1
#endif
#endif

__device__ inline float bf2f(ushort u) {
    union { uint i; float f; } x; x.i = ((uint)u) << 16; return x.f;
}
__device__ inline ushort f2bf(float f) {
    union { float f; uint i; } x; x.f = f;
    uint r = x.i + 0x7FFF + ((x.i >> 16) & 1);   // RNE
    return (ushort)(r >> 16);
}
__device__ inline float lrelu(float e) { return (e > 0.f) ? e : NEG_SLOPE * e; }

// ---- manual OCP e4m3fn encode/decode (fallback path) ----
__device__ inline uint f2e4m3(float f) {
    uint bits = __float_as_uint(f);
    uint s = (bits >> 24) & 0x80;
    float af = __uint_as_float(bits & 0x7FFFFFFF);
    af = fminf(af, 448.f);
    uint out;
    if (af < 0.015625f) {
        out = (uint)rintf(af * 512.f);
    } else {
        uint ab = __float_as_uint(af);
        uint r = ab + 0x0007FFFFu + ((ab >> 20) & 1u);
        int e2 = (int)((r >> 23) & 0xFF) - 127;
        uint m3 = (r >> 20) & 7u;
        if (e2 > 8) { e2 = 8; m3 = 6; }
        out = ((uint)(e2 + 7) << 3) | m3;
    }
    return s | out;
}
__device__ inline float e4m32f(uint u) {
    uint exp = (u >> 3) & 0xF;
    uint m = u & 7u;
    float mant = (float)((exp ? 8u : 0u) | m);
    uint e = (exp ? exp : 1u) + 117u;
    float v = mant * __uint_as_float(e << 23);
    return (u & 0x80) ? -v : v;
}

__device__ inline uchar enc8(float v) {
#ifdef HAS_HW_FP8
    return (uchar)(__builtin_amdgcn_cvt_pk_fp8_f32(v, v, 0, false) & 0xFF);
#else
    return (uchar)f2e4m3(v);
#endif
}

// accumulate 4 fp8 (one uint) weighted by a2 into two f32x2 accumulators
__device__ inline void acc4(f32x2 a2, uint w, f32x2& lo, f32x2& hi) {
#ifdef HAS_HW_FP8
    f32x2 p0 = __builtin_amdgcn_cvt_pk_f32_fp8((int)w, false);
    f32x2 p1 = __builtin_amdgcn_cvt_pk_f32_fp8((int)w, true);
    lo += a2 * p0;
    hi += a2 * p1;
#else
    lo[0] += a2[0] * e4m32f(w & 255);
    lo[1] += a2[1] * e4m32f((w >> 8) & 255);
    hi[0] += a2[0] * e4m32f((w >> 16) & 255);
    hi[1] += a2[1] * e4m32f(w >> 24);
#endif
}

// ---------------- CSR build: 2-level bucket counting sort (packed pairs) ----------------

__global__ __launch_bounds__(256) void bucket_hist(const int* __restrict__ dst,
                                                   int* __restrict__ chunkCnt) {
    __shared__ int cnt[NBUCK];
    int t = threadIdx.x, blk = blockIdx.x;
    for (int b = t; b < NBUCK; b += 256) cnt[b] = 0;
    __syncthreads();
    int beg = blk * CHUNK_SZ, end = min(beg + CHUNK_SZ, N_EDGES);
    for (int i = beg + t; i < end; i += 256) atomicAdd(&cnt[dst[i] >> 8], 1);
    __syncthreads();
    for (int b = t; b < NBUCK; b += 256) chunkCnt[blk * NBUCK + b] = cnt[b];
}

__global__ __launch_bounds__(512) void bucket_scan(const int* __restrict__ chunkCnt,
                                                   int* __restrict__ chunkBase,
                                                   int* __restrict__ bucketBase) {
    __shared__ int tot[512];
    int b = threadIdx.x;
    int run = 0;
    if (b < NBUCK) {
        for (int c = 0; c < NCHUNK; ++c) {
            chunkBase[c * NBUCK + b] = run;
            run += chunkCnt[c * NBUCK + b];
        }
    }
    tot[b] = (b < NBUCK) ? run : 0;
    __syncthreads();
    for (int off = 1; off < 512; off <<= 1) {
        int x = (b >= off) ? tot[b - off] : 0;
        __syncthreads();
        tot[b] += x;
        __syncthreads();
    }
    if (b == 0) bucketBase[0] = 0;
    if (b < NBUCK) bucketBase[b + 1] = tot[b];
}

__global__ __launch_bounds__(256) void bucket_scatter(const int* __restrict__ src,
                                                      const int* __restrict__ dst,
                                                      const int* __restrict__ chunkBase,
                                                      const int* __restrict__ bucketBase,
                                                      int* __restrict__ pairs) {
    __shared__ int cur[NBUCK];
    int t = threadIdx.x, blk = blockIdx.x;
    for (int b = t; b < NBUCK; b += 256)
        cur[b] = bucketBase[b] + chunkBase[blk * NBUCK + b];
    __syncthreads();
    int beg = blk * CHUNK_SZ, end = min(beg + CHUNK_SZ, N_EDGES);
    for (int i = beg + t; i < end; i += 256) {
        int d = dst[i];
        int pos = atomicAdd(&cur[d >> 8], 1);
        pairs[pos] = (src[i] << 8) | (d & 255);
    }
}

__global__ __launch_bounds__(256) void bucket_build(const int* __restrict__ pairs,
                                                    const int* __restrict__ bucketBase,
                                                    int* __restrict__ rowptr,
                                                    int* __restrict__ csr) {
    __shared__ int cnt[256], pre[256];
    int b = blockIdx.x, t = threadIdx.x;
    cnt[t] = 0;
    __syncthreads();
    int beg = bucketBase[b], end = bucketBase[b + 1];
    for (int i = beg + t; i < end; i += 256) atomicAdd(&cnt[pairs[i] & 255], 1);
    __syncthreads();
    int v = cnt[t];
    pre[t] = v;
    __syncthreads();
    for (int off = 1; off < 256; off <<= 1) {
        int x = (t >= off) ? pre[t - off] : 0;
        __syncthreads();
        pre[t] += x;
        __syncthreads();
    }
    int excl = pre[t] - v;
    int node = b * 256 + t;
    if (node <= N_NODES) rowptr[node] = beg + excl;
    cnt[t] = excl;
    __syncthreads();
    for (int i = beg + t; i < end; i += 256) {
        int p = pairs[i];
        int pos = beg + atomicAdd(&cnt[p & 255], 1);
        csr[pos] = p >> 8;
    }
}

// ---------------- merged weight transpose/convert (W1+W2+W3) ----------------
__global__ void transpose_w_all(const float* __restrict__ W1, const float* __restrict__ W2,
                                const float* __restrict__ W3, ushort* __restrict__ BT1,
                                ushort* __restrict__ BT2, ushort* __restrict__ BT3) {
    int i = blockIdx.x * blockDim.x + threadIdx.x;
    if (i < 32768) {                       // W1 [256][128] -> BT1 [128][256]
        int n = i >> 8, k = i & 255;
        BT1[i] = f2bf(W1[(size_t)k * 128 + n]);
    } else if (i < 49152) {                // W2 [128][128] -> BT2 [128][128]
        int j = i - 32768;
        int n = j >> 7, k = j & 127;
        BT2[j] = f2bf(W2[(size_t)k * 128 + n]);
    } else if (i < 55296) {                // W3 [128][40] -> BT3 [48][128] (pad)
        int j = i - 49152;
        int n = j >> 7, k = j & 127;
        BT3[j] = f2bf((n < 40) ? W3[(size_t)k * 40 + n] : 0.f);
    }
}

// ---------------- GEMM1: fp32 X (K=256) -> fp8 table + As/Ad (4 heads) ----------------

__global__ __launch_bounds__(256) void mfma_gemm1(const float* __restrict__ X,
                                                  const ushort* __restrict__ BT,
                                                  const float* __restrict__ asv,
                                                  const float* __restrict__ adv,
                                                  uchar* __restrict__ X8,
                                                  float* __restrict__ As,
                                                  float* __restrict__ Ad) {
    __shared__ ushort Ats[64][40];
    __shared__ ushort Bs[128][40];
    __shared__ float sA[64][4], sD[64][4];
    int m0 = blockIdx.x * 64;
    int t = threadIdx.x;
    int wave = t >> 6, lane = t & 63;
    int wm = wave >> 1, wn = wave & 1;
    f32x4 acc[2][4] = {};
    for (int kt = 0; kt < 256; kt += 32) {
        {
            int r = t >> 2, kg = (t & 3) << 3;
            int rr = (m0 + r < N_NODES) ? m0 + r : N_NODES - 1;
            float4 xa = *(const float4*)&X[(size_t)rr * 256 + kt + kg];
            float4 xb = *(const float4*)&X[(size_t)rr * 256 + kt + kg + 4];
            ushort o[8] = { f2bf(xa.x), f2bf(xa.y), f2bf(xa.z), f2bf(xa.w),
                            f2bf(xb.x), f2bf(xb.y), f2bf(xb.z), f2bf(xb.w) };
            *(s16x8*)&Ats[r][kg] = *(s16x8*)o;
        }
        #pragma unroll
        for (int i = 0; i < 2; ++i) {
            int idx = t + (i << 8);
            int r = idx >> 2, kg = (idx & 3) << 3;
            *(s16x8*)&Bs[r][kg] = *(const s16x8*)&BT[(size_t)r * 256 + kt + kg];
        }
        __syncthreads();
        int row = lane & 15, koff = (lane >> 4) << 3;
        s16x8 a[2], b[4];
        #pragma unroll
        for (int mf = 0; mf < 2; ++mf)
            a[mf] = *(s16x8*)&Ats[wm * 32 + mf * 16 + row][koff];
        #pragma unroll
        for (int nf = 0; nf < 4; ++nf)
            b[nf] = *(s16x8*)&Bs[wn * 64 + nf * 16 + row][koff];
        #pragma unroll
        for (int mf = 0; mf < 2; ++mf)
            #pragma unroll
            for (int nf = 0; nf < 4; ++nf)
                acc[mf][nf] = __builtin_amdgcn_mfma_f32_16x16x32_bf16(a[mf], b[nf], acc[mf][nf], 0, 0, 0);
        __syncthreads();
    }
    int colb = lane & 15, rowb = (lane >> 4) << 2;
    float a0 = asv[wn * 64 + colb],      d0 = adv[wn * 64 + colb];
    float a1 = asv[wn * 64 + 16 + colb], d1 = adv[wn * 64 + 16 + colb];
    float a2 = asv[wn * 64 + 32 + colb], d2 = adv[wn * 64 + 32 + colb];
    float a3 = asv[wn * 64 + 48 + colb], d3 = adv[wn * 64 + 48 + colb];
    #pragma unroll
    for (int mf = 0; mf < 2; ++mf)
        #pragma unroll
        for (int reg = 0; reg < 4; ++reg) {
            float v0 = acc[mf][0][reg], v1 = acc[mf][1][reg];
            float v2 = acc[mf][2][reg], v3 = acc[mf][3][reg];
            float sLo = v0 * a0 + v1 * a1, sHi = v2 * a2 + v3 * a3;
            float dLo = v0 * d0 + v1 * d1, dHi = v2 * d2 + v3 * d3;
            #pragma unroll
            for (int off = 1; off < 16; off <<= 1) {
                sLo += __shfl_xor(sLo, off, 64); sHi += __shfl_xor(sHi, off, 64);
                dLo += __shfl_xor(dLo, off, 64); dHi += __shfl_xor(dHi, off, 64);
            }
            if (colb == 0) {
                int r = wm * 32 + mf * 16 + rowb + reg;
                sA[r][wn * 2] = sLo; sA[r][wn * 2 + 1] = sHi;
                sD[r][wn * 2] = dLo; sD[r][wn * 2 + 1] = dHi;
            }
        }
    #pragma unroll
    for (int mf = 0; mf < 2; ++mf)
        #pragma unroll
        for (int nf = 0; nf < 4; ++nf)
            #pragma unroll
            for (int reg = 0; reg < 4; ++reg) {
                int row = m0 + wm * 32 + mf * 16 + rowb + reg;
                int col = wn * 64 + nf * 16 + colb;
                if (row < N_NODES) X8[(size_t)row * 128 + col] = enc8(acc[mf][nf][reg]);
            }
    __syncthreads();
    {
        int r = t >> 2, h = t & 3;
        int node = m0 + r;
        if (node < N_NODES) {
            As[(size_t)node * 4 + h] = sA[r][h];
            Ad[(size_t)node * 4 + h] = sD[r][h];
        }
    }
}

// ---------------- GEMM2: bf16 in (K=128) -> fp8 table + As/Ad (1 head) ----------------

__global__ __launch_bounds__(256) void mfma_gemm2(const ushort* __restrict__ X,
                                                  const ushort* __restrict__ BT,
                                                  const float* __restrict__ asv,
                                                  const float* __restrict__ adv,
                                                  uchar* __restrict__ X8,
                                                  float* __restrict__ As,
                                                  float* __restrict__ Ad) {
    __shared__ ushort Ats[64][40];
    __shared__ ushort Bs[128][40];
    __shared__ float sA1[64], sD1[64];
    int m0 = blockIdx.x * 64;
    int t = threadIdx.x;
    int wave = t >> 6, lane = t & 63;
    int wm = wave >> 1, wn = wave & 1;
    f32x4 acc[2][4] = {};
    for (int kt = 0; kt < 128; kt += 32) {
        {
            int r = t >> 2, kg = (t & 3) << 3;
            *(s16x8*)&Ats[r][kg] = *(const s16x8*)&X[(size_t)(m0 + r) * 128 + kt + kg];
        }
        #pragma unroll
        for (int i = 0; i < 2; ++i) {
            int idx = t + (i << 8);
            int r = idx >> 2, kg = (idx & 3) << 3;
            *(s16x8*)&Bs[r][kg] = *(const s16x8*)&BT[(size_t)r * 128 + kt + kg];
        }
        __syncthreads();
        int row = lane & 15, koff = (lane >> 4) << 3;
        s16x8 a[2], b[4];
        #pragma unroll
        for (int mf = 0; mf < 2; ++mf)
            a[mf] = *(s16x8*)&Ats[wm * 32 + mf * 16 + row][koff];
        #pragma unroll
        for (int nf = 0; nf < 4; ++nf)
            b[nf] = *(s16x8*)&Bs[wn * 64 + nf * 16 + row][koff];
        #pragma unroll
        for (int mf = 0; mf < 2; ++mf)
            #pragma unroll
            for (int nf = 0; nf < 4; ++nf)
                acc[mf][nf] = __builtin_amdgcn_mfma_f32_16x16x32_bf16(a[mf], b[nf], acc[mf][nf], 0, 0, 0);
        __syncthreads();
    }
    if (t < 64) { sA1[t] = 0.f; sD1[t] = 0.f; }
    __syncthreads();
    int colb = lane & 15, rowb = (lane >> 4) << 2;
    float a0 = asv[wn * 64 + colb],      d0 = adv[wn * 64 + colb];
    float a1 = asv[wn * 64 + 16 + colb], d1 = adv[wn * 64 + 16 + colb];
    float a2 = asv[wn * 64 + 32 + colb], d2 = adv[wn * 64 + 32 + colb];
    float a3 = asv[wn * 64 + 48 + colb], d3 = adv[wn * 64 + 48 + colb];
    #pragma unroll
    for (int mf = 0; mf < 2; ++mf)
        #pragma unroll
        for (int reg = 0; reg < 4; ++reg) {
            float v0 = acc[mf][0][reg], v1 = acc[mf][1][reg];
            float v2 = acc[mf][2][reg], v3 = acc[mf][3][reg];
            float s = v0 * a0 + v1 * a1 + v2 * a2 + v3 * a3;
            float d = v0 * d0 + v1 * d1 + v2 * d2 + v3 * d3;
            #pragma unroll
            for (int off = 1; off < 16; off <<= 1) {
                s += __shfl_xor(s, off, 64);
                d += __shfl_xor(d, off, 64);
            }
            if (colb == 0) {
                int r = wm * 32 + mf * 16 + rowb + reg;
                atomicAdd(&sA1[r], s);
                atomicAdd(&sD1[r], d);
            }
        }
    #pragma unroll
    for (int mf = 0; mf < 2; ++mf)
        #pragma unroll
        for (int nf = 0; nf < 4; ++nf)
            #pragma unroll
            for (int reg = 0; reg < 4; ++reg) {
                int row = m0 + wm * 32 + mf * 16 + rowb + reg;
                int col = wn * 64 + nf * 16 + colb;
                if (row < N_NODES) X8[(size_t)row * 128 + col] = enc8(acc[mf][nf][reg]);
            }
    __syncthreads();
    if (t < 64) {
        int node = m0 + t;
        if (node < N_NODES) { As[node] = sA1[t]; Ad[node] = sD1[t]; }
    }
}

// ---------------- GEMM3: bf16 in (K=128), 40 cols -> fp8 table (stride 64) + As/Ad ----------------

__global__ __launch_bounds__(256) void mfma_gemm3(const ushort* __restrict__ X,
                                                  const ushort* __restrict__ BT,
                                                  const float* __restrict__ asv,
                                                  const float* __restrict__ adv,
                                                  uchar* __restrict__ X8,
                                                  float* __restrict__ As,
                                                  float* __restrict__ Ad) {
    __shared__ ushort Ats[64][40];
    __shared__ ushort Bs[48][40];
    int m0 = blockIdx.x * 64;
    int t = threadIdx.x, wave = t >> 6, lane = t & 63;
    f32x4 acc[3] = {};
    for (int kt = 0; kt < 128; kt += 32) {
        {
            int r = t >> 2, kg = (t & 3) << 3;
            *(s16x8*)&Ats[r][kg] = *(const s16x8*)&X[(size_t)(m0 + r) * 128 + kt + kg];
        }
        if (t < 192) {
            int r = t >> 2, kg = (t & 3) << 3;
            *(s16x8*)&Bs[r][kg] = *(const s16x8*)&BT[(size_t)r * 128 + kt + kg];
        }
        __syncthreads();
        int row = lane & 15, koff = (lane >> 4) << 3;
        s16x8 a = *(s16x8*)&Ats[wave * 16 + row][koff];
        #pragma unroll
        for (int nf = 0; nf < 3; ++nf) {
            s16x8 b = *(s16x8*)&Bs[nf * 16 + row][koff];
            acc[nf] = __builtin_amdgcn_mfma_f32_16x16x32_bf16(a, b, acc[nf], 0, 0, 0);
        }
        __syncthreads();
    }
    int colb = lane & 15, rowb = (lane >> 4) << 2;
    float a0 = asv[colb],      d0 = adv[colb];
    float a1 = asv[16 + colb], d1 = adv[16 + colb];
    float a2 = (32 + colb < 40) ? asv[32 + colb] : 0.f;
    float d2 = (32 + colb < 40) ? adv[32 + colb] : 0.f;
    #pragma unroll
    for (int reg = 0; reg < 4; ++reg) {
        float s = acc[0][reg] * a0 + acc[1][reg] * a1 + acc[2][reg] * a2;
        float d = acc[0][reg] * d0 + acc[1][reg] * d1 + acc[2][reg] * d2;
        #pragma unroll
        for (int off = 1; off < 16; off <<= 1) {
            s += __shfl_xor(s, off, 64);
            d += __shfl_xor(d, off, 64);
        }
        if (colb == 0) {
            int node = m0 + wave * 16 + rowb + reg;
            if (node < N_NODES) { As[node] = s; Ad[node] = d; }
        }
    }
    #pragma unroll
    for (int nf = 0; nf < 3; ++nf)
        #pragma unroll
        for (int reg = 0; reg < 4; ++reg) {
            int row = m0 + wave * 16 + rowb + reg;
            int col = nf * 16 + colb;
            if (row < N_NODES) X8[(size_t)row * 64 + col] = enc8(acc[nf][reg]);
        }
}

// ---------------- single-pass aggregate from fp8 table (WD=128) ----------------
// 8 lanes cover a 128B row (16B uint4 each); 8 rows per round.

template <int NH>
__global__ void agg_fused_fp8(const uchar* __restrict__ X8, const float* __restrict__ As,
                              const float* __restrict__ Ad, const float* __restrict__ bias,
                              const int* __restrict__ rowptr, const int* __restrict__ csr,
                              ushort* __restrict__ Y) {
    int node = (int)((blockIdx.x * blockDim.x + threadIdx.x) >> 6);
    int lane = threadIdx.x & 63;
    if (node >= N_NODES) return;
    int sub = lane >> 3;            // 0..7: row within round
    int cg = (lane & 7) << 4;       // col group: 16 fp8 = 16B
    int hB = (NH == 4) ? (cg >> 5) : 0;
    float adiB = Ad[(size_t)node * NH + hB];
    int beg = rowptr[node], deg = rowptr[node + 1] - beg;
    int items = deg + 1;
    f32x2 acc2[8] = {};
    float den = 0.f;
    for (int base = 0; base < items; base += 8) {
        int i = base + sub;
        int src = (i < deg) ? csr[beg + i] : node;
        float e = As[(size_t)src * NH + hB] + adiB;
        float a = __expf(lrelu(e));
        if (i > deg) a = 0.f;
        den += a;
        f32x2 a2 = { a, a };
        uint4 rv = *(const uint4*)(X8 + (((uint)src << 7) + cg));
        acc4(a2, rv.x, acc2[0], acc2[1]);
        acc4(a2, rv.y, acc2[2], acc2[3]);
        acc4(a2, rv.z, acc2[4], acc2[5]);
        acc4(a2, rv.w, acc2[6], acc2[7]);
    }
    den += __shfl_xor(den, 8, 64);
    den += __shfl_xor(den, 16, 64);
    den += __shfl_xor(den, 32, 64);
    float* af = (float*)acc2;
    #pragma unroll
    for (int k = 0; k < 16; ++k) {
        af[k] += __shfl_xor(af[k], 8, 64);
        af[k] += __shfl_xor(af[k], 16, 64);
        af[k] += __shfl_xor(af[k], 32, 64);
    }
    if (sub == 0) {                 // lanes 0..7 write cols cg..cg+15 (bf16, 32B)
        float dinv = 1.0f / den;
        uint o[8];
        #pragma unroll
        for (int k = 0; k < 8; ++k) {
            float v0 = fmaxf(acc2[k][0] * dinv + bias[cg + 2 * k],     0.f);
            float v1 = fmaxf(acc2[k][1] * dinv + bias[cg + 2 * k + 1], 0.f);
            o[k] = (uint)f2bf(v0) | ((uint)f2bf(v1) << 16);
        }
        *reinterpret_cast<uint4*>(&Y[(size_t)node * 128 + cg]) = *reinterpret_cast<uint4*>(&o[0]);
        *reinterpret_cast<uint4*>(&Y[(size_t)node * 128 + cg + 8]) = *reinterpret_cast<uint4*>(&o[4]);
    }
}

// ---------------- single-pass aggregate + log-softmax (layer 3, fp8 stride-64) ----------------
// 8 lanes cover a 64B row (8B uint2 each); 8 rows per round.  (R13 shape)

__global__ void agg_l3_fp8(const uchar* __restrict__ X8, const float* __restrict__ As,
                           const float* __restrict__ Ad, const float* __restrict__ bias,
                           const int* __restrict__ rowptr, const int* __restrict__ csr,
                           float* __restrict__ Y) {
    int node = (int)((blockIdx.x * blockDim.x + threadIdx.x) >> 6);
    int lane = threadIdx.x & 63;
    if (node >= N_NODES) return;
    int sub = lane >> 3;            // 0..7: row within round
    int cg = (lane & 7) << 3;       // col group: 8 fp8 = 8B
    float adi = Ad[node];
    int beg = rowptr[node], deg = rowptr[node + 1] - beg;
    int items = deg + 1;
    f32x2 acc2[4] = {};
    float den = 0.f;
    for (int base = 0; base < items; base += 8) {
        int i = base + sub;
        int src = (i < deg) ? csr[beg + i] : node;
        float a = __expf(lrelu(As[src] + adi));
        if (i > deg) a = 0.f;
        den += a;
        f32x2 a2 = { a, a };
        uint2 rv = *(const uint2*)(X8 + (((uint)src << 6) + cg));
        acc4(a2, rv.x, acc2[0], acc2[1]);
        acc4(a2, rv.y, acc2[2], acc2[3]);
    }
    den += __shfl_xor(den, 8, 64);
    den += __shfl_xor(den, 16, 64);
    den += __shfl_xor(den, 32, 64);
    float* af = (float*)acc2;
    #pragma unroll
    for (int k = 0; k < 8; ++k) {
        af[k] += __shfl_xor(af[k], 8, 64);
        af[k] += __shfl_xor(af[k], 16, 64);
        af[k] += __shfl_xor(af[k], 32, 64);
    }
    // lanes 0..4 hold valid col-groups (cg 0..32, 8 cols each = 40 total)
    bool valid = (lane < 5);
    float v[8];
    float pm = -1e30f;
    if (valid) {
        float dinv = 1.0f / den;
        #pragma unroll
        for (int k = 0; k < 8; ++k) {
            v[k] = af[k] * dinv + bias[cg + k];
            pm = fmaxf(pm, v[k]);
        }
    }
    #pragma unroll
    for (int off = 1; off < 8; off <<= 1) pm = fmaxf(pm, __shfl_xor(pm, off, 64));
    float ps = 0.f;
    if (valid) {
        #pragma unroll
        for (int k = 0; k < 8; ++k) ps += __expf(v[k] - pm);
    }
    #pragma unroll
    for (int off = 1; off < 8; off <<= 1) ps += __shfl_xor(ps, off, 64);
    if (valid) {
        float lden = __logf(ps);
        float4 o0 = make_float4(v[0] - pm - lden, v[1] - pm - lden,
                                v[2] - pm - lden, v[3] - pm - lden);
        float4 o1 = make_float4(v[4] - pm - lden, v[5] - pm - lden,
                                v[6] - pm - lden, v[7] - pm - lden);
        *reinterpret_cast<float4*>(&Y[(size_t)node * 40 + cg]) = o0;
        *reinterpret_cast<float4*>(&Y[(size_t)node * 40 + cg + 4]) = o1;
    }
}

// ---------------- launch ----------------

static inline size_t align256(size_t x) { return (x + 255) & ~(size_t)255; }

extern "C" void kernel_launch(void* const* d_in, const int* in_sizes, int n_in,
                              void* d_out, int out_size, void* d_ws, size_t ws_size,
                              hipStream_t stream) {
    const int*   edge = (const int*)d_in[0];
    const float* feat = (const float*)d_in[1];
    const float* W1   = (const float*)d_in[2];
    const float* as1  = (const float*)d_in[3];
    const float* ad1  = (const float*)d_in[4];
    const float* b1   = (const float*)d_in[5];
    const float* W2   = (const float*)d_in[6];
    const float* as2  = (const float*)d_in[7];
    const float* ad2  = (const float*)d_in[8];
    const float* b2   = (const float*)d_in[9];
    const float* W3   = (const float*)d_in[10];
    const float* as3  = (const float*)d_in[11];
    const float* ad3  = (const float*)d_in[12];
    const float* b3   = (const float*)d_in[13];
    float* out = (float*)d_out;

    const int* srcArr = edge;
    const int* dstArr = edge + N_EDGES;

    const size_t NB128 = (size_t)N_NODES * 128 * 2;   // 25.6 MB

    char* w = (char*)d_ws;
    char* regionA = w; w += align256(2 * NB128);      // pairs -> x8_2 | h2
    char* regionB = w; w += align256(NB128);          // x8_1 ; x8_3 at +NB128/2
    char* regionC = w; w += align256(NB128);          // h1
    float* As   = (float*)w; w += align256((size_t)N_NODES * 4 * 4);
    float* Ad   = (float*)w; w += align256((size_t)N_NODES * 4 * 4);
    int* rowptr = (int*)w;   w += align256((size_t)(N_NODES + 1) * 4);
    int* csr    = (int*)w;   w += align256((size_t)N_EDGES * 4);
    int* chunkCnt  = (int*)w; w += align256((size_t)NCHUNK * NBUCK * 4);
    int* chunkBase = (int*)w; w += align256((size_t)NCHUNK * NBUCK * 4);
    int* bucketBase = (int*)w; w += align256((size_t)(NBUCK + 1) * 4);
    ushort* WT1 = (ushort*)w; w += align256((size_t)128 * 256 * 2);
    ushort* WT2 = (ushort*)w; w += align256((size_t)128 * 128 * 2);
    ushort* WT3 = (ushort*)w; w += align256((size_t)48 * 128 * 2);

    int* pairs = (int*)regionA;                       // packed, dead before x8_2

    uchar*  x8_1 = (uchar*)regionB;                   // [100k][128] fp8
    uchar*  x8_3 = (uchar*)(regionB + NB128 / 2);     // [100k][64]  fp8
    ushort* h1   = (ushort*)regionC;                  // [100k][128] bf16
    uchar*  x8_2 = (uchar*)regionA;                   // [100k][128] fp8
    ushort* h2   = (ushort*)(regionA + NB128);        // [100k][128] bf16

    // ---- CSR build ----
    bucket_hist<<<NCHUNK, 256, 0, stream>>>(dstArr, chunkCnt);
    bucket_scan<<<1, 512, 0, stream>>>(chunkCnt, chunkBase, bucketBase);
    bucket_scatter<<<NCHUNK, 256, 0, stream>>>(srcArr, dstArr, chunkBase, bucketBase, pairs);
    bucket_build<<<NBUCK, 256, 0, stream>>>(pairs, bucketBase, rowptr, csr);

    // weights (merged)
    transpose_w_all<<<(55296 + 255) / 256, 256, 0, stream>>>(W1, W2, W3, WT1, WT2, WT3);

    int aggGrid = (N_NODES + 3) / 4;
    int gemmGrid = (N_NODES + 63) / 64;

    // ---- layer 1 ----
    mfma_gemm1<<<gemmGrid, 256, 0, stream>>>(feat, WT1, as1, ad1, x8_1, As, Ad);
    agg_fused_fp8<4><<<aggGrid, 256, 0, stream>>>(x8_1, As, Ad, b1, rowptr, csr, h1);

    // ---- layer 2 ----
    mfma_gemm2<<<gemmGrid, 256, 0, stream>>>(h1, WT2, as2, ad2, x8_2, As, Ad);
    agg_fused_fp8<1><<<aggGrid, 256, 0, stream>>>(x8_2, As, Ad, b2, rowptr, csr, h2);

    // ---- layer 3 ----
    mfma_gemm3<<<gemmGrid, 256, 0, stream>>>(h2, WT3, as3, ad3, x8_3, As, Ad);
    agg_l3_fp8<<<aggGrid, 256, 0, stream>>>(x8_3, As, Ad, b3, rowptr, csr, out);
}